// Round 10
// baseline (705.026 us; speedup 1.0000x reference)
//
#include <hip/hip_runtime.h>
#include <math.h>

#define EPS 1e-5f
#define SQRT3F 1.7320508075688772f

__device__ __forceinline__ float wsum64(float x) {
#pragma unroll
    for (int o = 32; o > 0; o >>= 1) x += __shfl_xor(x, o, 64);
    return x;
}
__device__ __forceinline__ float hsum32(float x) {
#pragma unroll
    for (int o = 16; o > 0; o >>= 1) x += __shfl_xor(x, o, 64);
    return x;
}
__device__ __forceinline__ float sigm(float x) { return 1.f / (1.f + __expf(-x)); }
__device__ __forceinline__ float siluf(float x) { return x * sigm(x); }

// ---------------------------------------------------------------------------
// Kernel 1 (fused): blocks [0, nb_pre): per-node preprocessing (+points4);
// blocks [nb_pre, ...): CSR degree histogram.
// ---------------------------------------------------------------------------
__global__ __launch_bounds__(256) void pre_and_hist(
    int N, int E, int nb_pre,
    const float* __restrict__ feats, const float* __restrict__ equ,
    const int* __restrict__ nbrs, const float* __restrict__ points,
    const float* __restrict__ ln1_w, const float* __restrict__ ln1_b,
    const float* __restrict__ eqn1_w, const float* __restrict__ eqn1_b,
    const float* __restrict__ inv_fc_w, const float* __restrict__ inv_fc_b,
    const float* __restrict__ equ_fc_w, const float* __restrict__ Winv,
    float* __restrict__ feats_ln, float* __restrict__ equ_ln,
    float* __restrict__ equ1t, float* __restrict__ PsP, float* __restrict__ PtP,
    float* __restrict__ points4, int* __restrict__ deg)
{
    if (blockIdx.x >= nb_pre) {
        int i = (blockIdx.x - nb_pre) * 256 + threadIdx.x;
        if (i < E) atomicAdd(&deg[nbrs[E + i]], 1);
        return;
    }

    __shared__ float fl_s[4][128];
    __shared__ float el_s[4][128];
    __shared__ float f1_s[4][32];
    const int w = threadIdx.x >> 6;
    const int lane = threadIdx.x & 63;
    const int n = blockIdx.x * 4 + w;
    const bool act = n < N;
    const int c = lane & 31;
    const int half = lane >> 5;

    if (act && lane == 0) {
        float4 p;
        p.x = points[n * 3 + 0]; p.y = points[n * 3 + 1];
        p.z = points[n * 3 + 2]; p.w = 0.f;
        *(float4*)&points4[n * 4] = p;
    }

    float x0 = 0.f, x1 = 0.f;
    if (act) { x0 = feats[n * 128 + lane]; x1 = feats[n * 128 + 64 + lane]; }
    float s  = wsum64(x0 + x1);
    float sq = wsum64(x0 * x0 + x1 * x1);
    float mu = s * (1.f / 128.f);
    float var = sq * (1.f / 128.f) - mu * mu;
    float rs = rsqrtf(var + EPS);
    float y0 = (x0 - mu) * rs * ln1_w[lane] + ln1_b[lane];
    float y1 = (x1 - mu) * rs * ln1_w[64 + lane] + ln1_b[64 + lane];
    if (act) { feats_ln[n * 128 + lane] = y0; feats_ln[n * 128 + 64 + lane] = y1; }
    fl_s[w][lane] = y0; fl_s[w][64 + lane] = y1;

    float a = 0.f, b = 0.f;
    if (act) { a = equ[n * 128 + lane]; b = equ[n * 128 + 64 + lane]; }
    float a0 = (half == 0) ? a : 0.f;
    float m0 = wsum64(a0) * (1.f / 32.f);
    float f0 = a0 - m0;
    float n0 = wsum64((half == 0) ? f0 * f0 : 0.f) * (1.f / 32.f);
    float rs0 = rsqrtf(n0 + EPS);
    float sq1 = ((half == 1) ? a * a : 0.f) + b * b;
    float n1 = wsum64(sq1) * (1.f / 96.f);
    float rs1 = rsqrtf(n1 + EPS);
    float w1c = eqn1_w[32 + c];
    float ea = (half == 0) ? (f0 * rs0 * eqn1_w[c] + eqn1_b[c]) : (a * rs1 * w1c);
    float eb = b * rs1 * w1c;
    if (act) { equ_ln[n * 128 + lane] = ea; equ_ln[n * 128 + 64 + lane] = eb; }
    el_s[w][lane] = ea; el_s[w][64 + lane] = eb;

    __syncthreads();

    {
        float acc = 0.f;
#pragma unroll 8
        for (int k = 0; k < 64; k++) {
            int kk = half * 64 + k;
            acc += fl_s[w][kk] * inv_fc_w[kk * 32 + c];
        }
        acc += __shfl_xor(acc, 32);
        if (half == 0) f1_s[w][c] = acc + inv_fc_b[c];
    }
    if (act) {
        float acc = 0.f, acc2 = 0.f;
#pragma unroll 8
        for (int k = 0; k < 32; k++) {
            float wv = equ_fc_w[k * 32 + c];
            acc  += el_s[w][half * 32 + k] * wv;
            acc2 += el_s[w][(half + 2) * 32 + k] * wv;
        }
        equ1t[n * 128 + c * 4 + half]     = acc;
        equ1t[n * 128 + c * 4 + half + 2] = acc2;
    }
    __syncthreads();
    if (!act) return;

    {
        const int jj = c;
        float4 aPs = {0.f, 0.f, 0.f, 0.f};
        float4 aPt = {0.f, 0.f, 0.f, 0.f};
#pragma unroll 4
        for (int k = 0; k < 16; k++) {
            int kk = half * 16 + k;
            float x = f1_s[w][kk];
            float4 w4 = *(const float4*)&Winv[kk * 128 + jj * 4];
            float4 v4 = *(const float4*)&Winv[(32 + kk) * 128 + jj * 4];
            aPs.x += x * w4.x; aPs.y += x * w4.y; aPs.z += x * w4.z; aPs.w += x * w4.w;
            aPt.x += x * v4.x; aPt.y += x * v4.y; aPt.z += x * v4.z; aPt.w += x * v4.w;
        }
        aPs.x += __shfl_xor(aPs.x, 32); aPs.y += __shfl_xor(aPs.y, 32);
        aPs.z += __shfl_xor(aPs.z, 32); aPs.w += __shfl_xor(aPs.w, 32);
        aPt.x += __shfl_xor(aPt.x, 32); aPt.y += __shfl_xor(aPt.y, 32);
        aPt.z += __shfl_xor(aPt.z, 32); aPt.w += __shfl_xor(aPt.w, 32);
        if (half == 0) {
            const float* ps = (const float*)&aPs;
            const float* pt = (const float*)&aPt;
#pragma unroll
            for (int i = 0; i < 4; i++) {
                int m = jj * 4 + i;
                PsP[n * 128 + (m & 31) * 4 + (m >> 5)] = ps[i];
                PtP[n * 128 + (m & 31) * 4 + (m >> 5)] = pt[i];
            }
        }
    }
}

// ---------------------------------------------------------------------------
// CSR scan (single block) + DESCENDING degree-bucket prefix + weight packing
// + perm pad init (slots [N, nblk*8) = -1).
// ---------------------------------------------------------------------------
__global__ __launch_bounds__(1024) void csr_scan(
    int N, int nblk, const int* __restrict__ deg,
    int* __restrict__ row_start, int* __restrict__ cursor,
    int* __restrict__ bucket_start, int* __restrict__ bucket_cursor,
    int* __restrict__ perm,
    const float* __restrict__ fe1, const float* __restrict__ fe2,
    const float* __restrict__ gate_w, const float* __restrict__ We2,
    float* __restrict__ fe1P, float* __restrict__ fe2P,
    float* __restrict__ gatePa, float* __restrict__ gatePb,
    float* __restrict__ We2P)
{
    __shared__ int part[1024];
    __shared__ int hist[64];
    const int t = threadIdx.x;

    if (t < 1024) {
        int g = t >> 7, r = t & 127, cc = r >> 2, i = r & 3;
        fe1P[t]   = fe1[(g * 4 + i) * 32 + cc];
        fe2P[t]   = fe2[(g * 4 + i) * 32 + cc];
        gatePa[t] = gate_w[(g * 4 + i) * 64 + cc];
        gatePb[t] = gate_w[(g * 4 + i) * 64 + 32 + cc];
        We2P[t]   = We2[(g * 4 + i) * 32 + cc];
    }
    if (t == 1) {
        for (int j = N; j < nblk * 8; j++) perm[j] = -1;
    }

    if (t < 64) hist[t] = 0;
    __syncthreads();

    const int per = (N + 1023) / 1024;
    const int base = t * per;
    int s = 0;
    for (int i = 0; i < per; i++) {
        int idx = base + i;
        if (idx < N) {
            int d = deg[idx];
            s += d;
            atomicAdd(&hist[d < 63 ? d : 63], 1);
        }
    }
    part[t] = s;
    __syncthreads();
    for (int off = 1; off < 1024; off <<= 1) {
        int v = (t >= off) ? part[t - off] : 0;
        __syncthreads();
        part[t] += v;
        __syncthreads();
    }
    int run = (t > 0) ? part[t - 1] : 0;
    for (int i = 0; i < per; i++) {
        int idx = base + i;
        if (idx < N) { row_start[idx] = run; cursor[idx] = run; run += deg[idx]; }
    }
    if (t == 0) {
        int acc = 0;
        for (int b = 63; b >= 0; b--) {   // DESCENDING degree order (LPT, R7)
            bucket_start[b] = acc;
            bucket_cursor[b] = acc;
            acc += hist[b];
        }
    }
}

// ---------------------------------------------------------------------------
// Fused scatter: blocks [0, nbE): CSR edge scatter; rest: descending perm.
// ---------------------------------------------------------------------------
__global__ __launch_bounds__(256) void scatter_all(
    int E, int N, int nbE,
    const int* __restrict__ nb, int* __restrict__ cursor, int* __restrict__ csr_src,
    const int* __restrict__ deg, int* __restrict__ bucket_cursor, int* __restrict__ perm)
{
    if (blockIdx.x < nbE) {
        int i = blockIdx.x * 256 + threadIdx.x;
        if (i < E) {
            int d = nb[E + i];
            int s = nb[i];
            int pos = atomicAdd(&cursor[d], 1);
            csr_src[pos] = s;
        }
    } else {
        int i = (blockIdx.x - nbE) * 256 + threadIdx.x;
        if (i < N) {
            int d = deg[i]; if (d > 63) d = 63;
            int pos = atomicAdd(&bucket_cursor[d], 1);
            perm[pos] = i;
        }
    }
}

// ---------------------------------------------------------------------------
// Kernel 2: per-DST aggregation + fused equ-gate chain + fused inv FFN.
// 32-lane group per dst, 8 dsts/block, descending-degree perm (R7 schedule).
// After the per-group epilogue (which LNs inv_pre in-register and stages h
// and inv_pre in LDS), one barrier, then waves 0-1 run the 128x128 FFN for
// the block's 8 nodes. Hot loop untouched; VGPR must stay <=128 (R5/R8).
// ---------------------------------------------------------------------------
__global__ __launch_bounds__(256) void edge_agg(
    int N,
    const int* __restrict__ perm,
    const int* __restrict__ row_start, const int* __restrict__ deg_arr,
    const int* __restrict__ csr_src,
    const float* __restrict__ points4, const float* __restrict__ equ1t,
    const float* __restrict__ PsP, const float* __restrict__ PtP,
    const float* __restrict__ feats_ln, const float* __restrict__ equ_ln,
    const float* __restrict__ Wl0g, const float* __restrict__ bl0g,
    const float* __restrict__ Winvg, const float* __restrict__ binvg,
    const float* __restrict__ We2P, const float* __restrict__ fe1P,
    const float* __restrict__ fe2P, const float* __restrict__ gatePa,
    const float* __restrict__ gatePb,
    const float* __restrict__ eqn2_w, const float* __restrict__ eqn2_b,
    const float* __restrict__ ffn_ln_w, const float* __restrict__ ffn_ln_b,
    const float* __restrict__ W1g, const float* __restrict__ b1g,
    const float* __restrict__ W2g, const float* __restrict__ b2g,
    float* __restrict__ out_inv, float* __restrict__ out_equ)
{
    __shared__ float WeP[32 * 128];   // 16 KB
    __shared__ float Wl0P[16 * 128];  //  8 KB
    __shared__ float BinvP[128];
    __shared__ float bl0s[32];
    __shared__ float scr[8][128];     //  4 KB
    __shared__ float invs[8][128];    //  4 KB  inv_pre per node
    __shared__ float htp[128 * 9];    //  4.5 KB h (then r), [k][node], pad 9
    __shared__ int   nid[8];

    for (int idx = threadIdx.x; idx < 4096; idx += 256) {
        int k = idx >> 7, r = idx & 127, cc = r >> 2, j = r & 3;
        WeP[idx] = Winvg[(64 + k) * 128 + j * 32 + cc];
    }
    for (int idx = threadIdx.x; idx < 2048; idx += 256) {
        int g = idx >> 7, r = idx & 127, cc = r >> 2, i = r & 3;
        Wl0P[idx] = Wl0g[(g * 4 + i) * 32 + cc];
    }
    if (threadIdx.x < 128) BinvP[threadIdx.x] = binvg[(threadIdx.x & 3) * 32 + (threadIdx.x >> 2)];
    if (threadIdx.x < 32) bl0s[threadIdx.x] = bl0g[threadIdx.x];
    __syncthreads();

    const int grp = threadIdx.x >> 5;
    const int c = threadIdx.x & 31;
    const int halfsel = grp & 1;
    const int gid = blockIdx.x * 8 + grp;
    const int n = perm[gid];
    if (c == 0) nid[grp] = n;
    const bool active = (n >= 0);

    if (active) {
        const int start = row_start[n];
        const int len = deg_arr[n];
        const float bl0c = bl0s[c];
        float4 te4 = *(const float4*)&equ1t[n * 128 + c * 4];
        float4 pt4 = *(const float4*)&PtP[n * 128 + c * 4];
        float4 pd4 = *(const float4*)&points4[n * 4];
        float4 base = *(const float4*)&BinvP[c * 4];
        base.x += pt4.x; base.y += pt4.y; base.z += pt4.z; base.w += pt4.w;

        float4 acc = {0.f, 0.f, 0.f, 0.f};
        float4 aer = {0.f, 0.f, 0.f, 0.f};
        int cnt = 0;
        int i = 0;

        for (; i + 2 <= len; i += 2) {
            const int s0 = csr_src[start + i];
            const int s1 = csr_src[start + i + 1];
            float4 a0 = *(const float4*)&equ1t[s0 * 128 + c * 4];
            float4 a1 = *(const float4*)&equ1t[s1 * 128 + c * 4];
            float4 p0 = *(const float4*)&PsP[s0 * 128 + c * 4];
            float4 p1 = *(const float4*)&PsP[s1 * 128 + c * 4];
            float4 q0 = *(const float4*)&points4[s0 * 4];
            float4 q1 = *(const float4*)&points4[s1 * 4];
            float dx0 = SQRT3F * (q0.x - pd4.x);
            float dy0 = SQRT3F * (q0.y - pd4.y);
            float dz0 = SQRT3F * (q0.z - pd4.z);
            float dx1 = SQRT3F * (q1.x - pd4.x);
            float dy1 = SQRT3F * (q1.y - pd4.y);
            float dz1 = SQRT3F * (q1.z - pd4.z);
            scr[grp][c]      = a0.x * te4.x + a0.y * te4.y + a0.z * te4.z + a0.w * te4.w;
            scr[grp][32 + c] = a0.x + a0.y * dx0 + a0.z * dy0 + a0.w * dz0;
            scr[grp][64 + c] = a1.x * te4.x + a1.y * te4.y + a1.z * te4.z + a1.w * te4.w;
            scr[grp][96 + c] = a1.x + a1.y * dx1 + a1.z * dy1 + a1.w * dz1;

            float e0acc = bl0c, e1acc = bl0c;
#pragma unroll
            for (int g = 0; g < 16; g++) {
                float4 w4 = *(const float4*)&Wl0P[g * 128 + c * 4];
                float4 d0 = *(const float4*)&scr[grp][g * 4];
                float4 d1 = *(const float4*)&scr[grp][64 + g * 4];
                e0acc += d0.x * w4.x + d0.y * w4.y + d0.z * w4.z + d0.w * w4.w;
                e1acc += d1.x * w4.x + d1.y * w4.y + d1.z * w4.z + d1.w * w4.w;
            }
            float el0_0 = siluf(e0acc);
            float el0_1 = siluf(e1acc);
            aer.x += el0_0 + el0_1;
            aer.y += a0.y + a1.y; aer.z += a0.z + a1.z; aer.w += a0.w + a1.w;
            scr[grp][c] = el0_0;
            scr[grp][32 + c] = el0_1;

            float4 m0 = base, m1 = base;
            m0.x += p0.x; m0.y += p0.y; m0.z += p0.z; m0.w += p0.w;
            m1.x += p1.x; m1.y += p1.y; m1.z += p1.z; m1.w += p1.w;
#pragma unroll
            for (int g = 0; g < 8; g++) {
                float4 x0 = *(const float4*)&scr[grp][g * 4];
                float4 x1 = *(const float4*)&scr[grp][32 + g * 4];
                const float* xp0 = (const float*)&x0;
                const float* xp1 = (const float*)&x1;
#pragma unroll
                for (int t = 0; t < 4; t++) {
                    float4 w4 = *(const float4*)&WeP[(g * 4 + t) * 128 + c * 4];
                    float v0 = xp0[t], v1 = xp1[t];
                    m0.x += v0 * w4.x; m0.y += v0 * w4.y; m0.z += v0 * w4.z; m0.w += v0 * w4.w;
                    m1.x += v1 * w4.x; m1.y += v1 * w4.y; m1.z += v1 * w4.z; m1.w += v1 * w4.w;
                }
            }
            m0.x = siluf(m0.x); m0.y = siluf(m0.y); m0.z = siluf(m0.z); m0.w = siluf(m0.w);
            m1.x = siluf(m1.x); m1.y = siluf(m1.y); m1.z = siluf(m1.z); m1.w = siluf(m1.w);
            acc.x += m0.x + m1.x; acc.y += m0.y + m1.y;
            acc.z += m0.z + m1.z; acc.w += m0.w + m1.w;
            float mx0 = fmaxf(fmaxf(m0.x, m0.y), fmaxf(m0.z, m0.w));
            float mx1 = fmaxf(fmaxf(m1.x, m1.y), fmaxf(m1.z, m1.w));
            unsigned long long b0 = __ballot(mx0 > 0.f);
            unsigned long long b1 = __ballot(mx1 > 0.f);
            cnt += ((unsigned int)(b0 >> (halfsel * 32)) != 0u);
            cnt += ((unsigned int)(b1 >> (halfsel * 32)) != 0u);
        }
        for (; i < len; i++) {
            const int s0 = csr_src[start + i];
            float4 a0 = *(const float4*)&equ1t[s0 * 128 + c * 4];
            float4 p0 = *(const float4*)&PsP[s0 * 128 + c * 4];
            float4 q0 = *(const float4*)&points4[s0 * 4];
            float dx0 = SQRT3F * (q0.x - pd4.x);
            float dy0 = SQRT3F * (q0.y - pd4.y);
            float dz0 = SQRT3F * (q0.z - pd4.z);
            scr[grp][c]      = a0.x * te4.x + a0.y * te4.y + a0.z * te4.z + a0.w * te4.w;
            scr[grp][32 + c] = a0.x + a0.y * dx0 + a0.z * dy0 + a0.w * dz0;
            float e0acc = bl0c;
#pragma unroll
            for (int g = 0; g < 16; g++) {
                float4 w4 = *(const float4*)&Wl0P[g * 128 + c * 4];
                float4 d0 = *(const float4*)&scr[grp][g * 4];
                e0acc += d0.x * w4.x + d0.y * w4.y + d0.z * w4.z + d0.w * w4.w;
            }
            float el0_0 = siluf(e0acc);
            aer.x += el0_0; aer.y += a0.y; aer.z += a0.z; aer.w += a0.w;
            scr[grp][c] = el0_0;
            float4 m0 = base;
            m0.x += p0.x; m0.y += p0.y; m0.z += p0.z; m0.w += p0.w;
#pragma unroll
            for (int g = 0; g < 8; g++) {
                float4 x0 = *(const float4*)&scr[grp][g * 4];
                const float* xp0 = (const float*)&x0;
#pragma unroll
                for (int t = 0; t < 4; t++) {
                    float4 w4 = *(const float4*)&WeP[(g * 4 + t) * 128 + c * 4];
                    float v0 = xp0[t];
                    m0.x += v0 * w4.x; m0.y += v0 * w4.y; m0.z += v0 * w4.z; m0.w += v0 * w4.w;
                }
            }
            m0.x = siluf(m0.x); m0.y = siluf(m0.y); m0.z = siluf(m0.z); m0.w = siluf(m0.w);
            acc.x += m0.x; acc.y += m0.y; acc.z += m0.z; acc.w += m0.w;
            float mx0 = fmaxf(fmaxf(m0.x, m0.y), fmaxf(m0.z, m0.w));
            unsigned long long b0 = __ballot(mx0 > 0.f);
            cnt += ((unsigned int)(b0 >> (halfsel * 32)) != 0u);
        }

        // ---- epilogue: inv_pre -> LDS + in-register LN -> h; full equ chain ----
        const float inv_nbn = 1.f / (1.f + (float)cnt);
        float4 im;
        im.x = (acc.x + feats_ln[n * 128 + c])      * inv_nbn;
        im.y = (acc.y + feats_ln[n * 128 + 32 + c]) * inv_nbn;
        im.z = (acc.z + feats_ln[n * 128 + 64 + c]) * inv_nbn;
        im.w = (acc.w + feats_ln[n * 128 + 96 + c]) * inv_nbn;
        invs[grp][c]      = im.x;
        invs[grp][32 + c] = im.y;
        invs[grp][64 + c] = im.z;
        invs[grp][96 + c] = im.w;
        float sm = hsum32(im.x + im.y + im.z + im.w) * (1.f / 128.f);
        float sv = hsum32(im.x * im.x + im.y * im.y + im.z * im.z + im.w * im.w)
                   * (1.f / 128.f) - sm * sm;
        float rsv = rsqrtf(sv + EPS);
        htp[c * 9 + grp]        = (im.x - sm) * rsv * ffn_ln_w[c]      + ffn_ln_b[c];
        htp[(32 + c) * 9 + grp] = (im.y - sm) * rsv * ffn_ln_w[32 + c] + ffn_ln_b[32 + c];
        htp[(64 + c) * 9 + grp] = (im.z - sm) * rsv * ffn_ln_w[64 + c] + ffn_ln_b[64 + c];
        htp[(96 + c) * 9 + grp] = (im.w - sm) * rsv * ffn_ln_w[96 + c] + ffn_ln_b[96 + c];

        // equ_new = (aer@We2 + equ_ln) / nbn, then eqn2-LN -> fe1 -> gate -> fe2
        *(float4*)&scr[grp][c * 4] = aer;
        float4 eo = {0.f, 0.f, 0.f, 0.f};
#pragma unroll
        for (int g = 0; g < 8; g++) {
            float4 w4 = *(const float4*)&We2P[g * 128 + c * 4];
            const float* wp = (const float*)&w4;
#pragma unroll
            for (int t = 0; t < 4; t++) {
                float4 a4 = *(const float4*)&scr[grp][(g * 4 + t) * 4];
                float wv = wp[t];
                eo.x += a4.x * wv; eo.y += a4.y * wv; eo.z += a4.z * wv; eo.w += a4.w * wv;
            }
        }
        float4 en;
        en.x = (eo.x + equ_ln[n * 128 + c])      * inv_nbn;
        en.y = (eo.y + equ_ln[n * 128 + 32 + c]) * inv_nbn;
        en.z = (eo.z + equ_ln[n * 128 + 64 + c]) * inv_nbn;
        en.w = (eo.w + equ_ln[n * 128 + 96 + c]) * inv_nbn;

        float m0e = hsum32(en.x) * (1.f / 32.f);
        float f0 = en.x - m0e;
        float n0 = hsum32(f0 * f0) * (1.f / 32.f);
        float rs0 = rsqrtf(n0 + EPS);
        float n1 = hsum32(en.y * en.y + en.z * en.z + en.w * en.w) * (1.f / 96.f);
        float rs1 = rsqrtf(n1 + EPS);
        float w1c = eqn2_w[32 + c];
        float4 ev;
        ev.x = f0 * rs0 * eqn2_w[c] + eqn2_b[c];
        ev.y = en.y * rs1 * w1c;
        ev.z = en.z * rs1 * w1c;
        ev.w = en.w * rs1 * w1c;
        *(float4*)&scr[grp][c * 4] = ev;

        float4 g4 = {0.f, 0.f, 0.f, 0.f};
#pragma unroll
        for (int g = 0; g < 8; g++) {
            float4 w4 = *(const float4*)&fe1P[g * 128 + c * 4];
            const float* wp = (const float*)&w4;
#pragma unroll
            for (int t = 0; t < 4; t++) {
                float4 a4 = *(const float4*)&scr[grp][(g * 4 + t) * 4];
                float wv = wp[t];
                g4.x += a4.x * wv; g4.y += a4.y * wv; g4.z += a4.z * wv; g4.w += a4.w * wv;
            }
        }
        scr[grp][c] = g4.x;

        float aftA = 0.f, aftB = 0.f;
#pragma unroll
        for (int g = 0; g < 8; g++) {
            float4 x4 = *(const float4*)&scr[grp][g * 4];
            float4 wa4 = *(const float4*)&gatePa[g * 128 + c * 4];
            float4 wb4 = *(const float4*)&gatePb[g * 128 + c * 4];
            aftA += x4.x * wa4.x + x4.y * wa4.y + x4.z * wa4.z + x4.w * wa4.w;
            aftB += x4.x * wb4.x + x4.y * wb4.y + x4.z * wb4.z + x4.w * wb4.w;
        }
        float mult = sigm(aftB);
        float4 G;
        G.x = siluf(aftA);
        G.y = g4.y * mult; G.z = g4.z * mult; G.w = g4.w * mult;
        *(float4*)&scr[grp][c * 4] = G;

        float4 oo = {0.f, 0.f, 0.f, 0.f};
#pragma unroll
        for (int g = 0; g < 8; g++) {
            float4 w4 = *(const float4*)&fe2P[g * 128 + c * 4];
            const float* wp = (const float*)&w4;
#pragma unroll
            for (int t = 0; t < 4; t++) {
                float4 a4 = *(const float4*)&scr[grp][(g * 4 + t) * 4];
                float wv = wp[t];
                oo.x += a4.x * wv; oo.y += a4.y * wv; oo.z += a4.z * wv; oo.w += a4.w * wv;
            }
        }
        out_equ[n * 128 + c]      = oo.x + en.x;
        out_equ[n * 128 + 32 + c] = oo.y + en.y;
        out_equ[n * 128 + 64 + c] = oo.z + en.z;
        out_equ[n * 128 + 96 + c] = oo.w + en.w;
    }

    // ---- fused FFN for the block's 8 nodes: waves 0-1, 4 nodes each ----
    __syncthreads();
    {
        const int wid = threadIdx.x >> 6;
        if (wid < 2) {
            const int half = (threadIdx.x >> 5) & 1;
            const int nb0 = wid * 4;
            float4 A0 = {0,0,0,0}, A1 = {0,0,0,0}, A2 = {0,0,0,0}, A3 = {0,0,0,0};
            for (int k = 0; k < 64; k++) {
                const int kk = half * 64 + k;
                float4 w4 = *(const float4*)&W1g[kk * 128 + c * 4];
                float x0 = htp[kk * 9 + nb0 + 0];
                float x1 = htp[kk * 9 + nb0 + 1];
                float x2 = htp[kk * 9 + nb0 + 2];
                float x3 = htp[kk * 9 + nb0 + 3];
                A0.x += x0 * w4.x; A0.y += x0 * w4.y; A0.z += x0 * w4.z; A0.w += x0 * w4.w;
                A1.x += x1 * w4.x; A1.y += x1 * w4.y; A1.z += x1 * w4.z; A1.w += x1 * w4.w;
                A2.x += x2 * w4.x; A2.y += x2 * w4.y; A2.z += x2 * w4.z; A2.w += x2 * w4.w;
                A3.x += x3 * w4.x; A3.y += x3 * w4.y; A3.z += x3 * w4.z; A3.w += x3 * w4.w;
            }
            A0.x += __shfl_xor(A0.x, 32); A0.y += __shfl_xor(A0.y, 32);
            A0.z += __shfl_xor(A0.z, 32); A0.w += __shfl_xor(A0.w, 32);
            A1.x += __shfl_xor(A1.x, 32); A1.y += __shfl_xor(A1.y, 32);
            A1.z += __shfl_xor(A1.z, 32); A1.w += __shfl_xor(A1.w, 32);
            A2.x += __shfl_xor(A2.x, 32); A2.y += __shfl_xor(A2.y, 32);
            A2.z += __shfl_xor(A2.z, 32); A2.w += __shfl_xor(A2.w, 32);
            A3.x += __shfl_xor(A3.x, 32); A3.y += __shfl_xor(A3.y, 32);
            A3.z += __shfl_xor(A3.z, 32); A3.w += __shfl_xor(A3.w, 32);
            if (half == 0) {
                float4 b4 = *(const float4*)&b1g[c * 4];
                htp[(4 * c + 0) * 9 + nb0 + 0] = fmaxf(A0.x + b4.x, 0.f);
                htp[(4 * c + 1) * 9 + nb0 + 0] = fmaxf(A0.y + b4.y, 0.f);
                htp[(4 * c + 2) * 9 + nb0 + 0] = fmaxf(A0.z + b4.z, 0.f);
                htp[(4 * c + 3) * 9 + nb0 + 0] = fmaxf(A0.w + b4.w, 0.f);
                htp[(4 * c + 0) * 9 + nb0 + 1] = fmaxf(A1.x + b4.x, 0.f);
                htp[(4 * c + 1) * 9 + nb0 + 1] = fmaxf(A1.y + b4.y, 0.f);
                htp[(4 * c + 2) * 9 + nb0 + 1] = fmaxf(A1.z + b4.z, 0.f);
                htp[(4 * c + 3) * 9 + nb0 + 1] = fmaxf(A1.w + b4.w, 0.f);
                htp[(4 * c + 0) * 9 + nb0 + 2] = fmaxf(A2.x + b4.x, 0.f);
                htp[(4 * c + 1) * 9 + nb0 + 2] = fmaxf(A2.y + b4.y, 0.f);
                htp[(4 * c + 2) * 9 + nb0 + 2] = fmaxf(A2.z + b4.z, 0.f);
                htp[(4 * c + 3) * 9 + nb0 + 2] = fmaxf(A2.w + b4.w, 0.f);
                htp[(4 * c + 0) * 9 + nb0 + 3] = fmaxf(A3.x + b4.x, 0.f);
                htp[(4 * c + 1) * 9 + nb0 + 3] = fmaxf(A3.y + b4.y, 0.f);
                htp[(4 * c + 2) * 9 + nb0 + 3] = fmaxf(A3.z + b4.z, 0.f);
                htp[(4 * c + 3) * 9 + nb0 + 3] = fmaxf(A3.w + b4.w, 0.f);
            }
            A0 = make_float4(0,0,0,0); A1 = make_float4(0,0,0,0);
            A2 = make_float4(0,0,0,0); A3 = make_float4(0,0,0,0);
            for (int k = 0; k < 64; k++) {
                const int kk = half * 64 + k;
                float4 w4 = *(const float4*)&W2g[kk * 128 + c * 4];
                float x0 = htp[kk * 9 + nb0 + 0];
                float x1 = htp[kk * 9 + nb0 + 1];
                float x2 = htp[kk * 9 + nb0 + 2];
                float x3 = htp[kk * 9 + nb0 + 3];
                A0.x += x0 * w4.x; A0.y += x0 * w4.y; A0.z += x0 * w4.z; A0.w += x0 * w4.w;
                A1.x += x1 * w4.x; A1.y += x1 * w4.y; A1.z += x1 * w4.z; A1.w += x1 * w4.w;
                A2.x += x2 * w4.x; A2.y += x2 * w4.y; A2.z += x2 * w4.z; A2.w += x2 * w4.w;
                A3.x += x3 * w4.x; A3.y += x3 * w4.y; A3.z += x3 * w4.z; A3.w += x3 * w4.w;
            }
            A0.x += __shfl_xor(A0.x, 32); A0.y += __shfl_xor(A0.y, 32);
            A0.z += __shfl_xor(A0.z, 32); A0.w += __shfl_xor(A0.w, 32);
            A1.x += __shfl_xor(A1.x, 32); A1.y += __shfl_xor(A1.y, 32);
            A1.z += __shfl_xor(A1.z, 32); A1.w += __shfl_xor(A1.w, 32);
            A2.x += __shfl_xor(A2.x, 32); A2.y += __shfl_xor(A2.y, 32);
            A2.z += __shfl_xor(A2.z, 32); A2.w += __shfl_xor(A2.w, 32);
            A3.x += __shfl_xor(A3.x, 32); A3.y += __shfl_xor(A3.y, 32);
            A3.z += __shfl_xor(A3.z, 32); A3.w += __shfl_xor(A3.w, 32);
            if (half == 0) {
                float4 b4 = *(const float4*)&b2g[c * 4];
                float4 A[4] = {A0, A1, A2, A3};
#pragma unroll
                for (int j = 0; j < 4; j++) {
                    const int nn = nid[nb0 + j];
                    if (nn >= 0) {
                        float4 r4 = *(const float4*)&invs[nb0 + j][c * 4];
                        float4 o;
                        o.x = A[j].x + b4.x + r4.x;
                        o.y = A[j].y + b4.y + r4.y;
                        o.z = A[j].z + b4.z + r4.z;
                        o.w = A[j].w + b4.w + r4.w;
                        *(float4*)&out_inv[(size_t)nn * 128 + c * 4] = o;
                    }
                }
            }
        }
    }
}

// ---------------------------------------------------------------------------
extern "C" void kernel_launch(void* const* d_in, const int* in_sizes, int n_in,
                              void* d_out, int out_size, void* d_ws, size_t ws_size,
                              hipStream_t stream)
{
    const float* feats     = (const float*)d_in[0];
    const float* equ       = (const float*)d_in[1];
    const float* points    = (const float*)d_in[2];
    const int*   neighbors = (const int*)d_in[3];
    const float* ln1_w     = (const float*)d_in[4];
    const float* ln1_b     = (const float*)d_in[5];
    const float* eqn1_w    = (const float*)d_in[6];
    const float* eqn1_b    = (const float*)d_in[7];
    const float* inv_fc_w  = (const float*)d_in[8];
    const float* inv_fc_b  = (const float*)d_in[9];
    const float* equ_fc_w  = (const float*)d_in[10];
    const float* fc_l0_w   = (const float*)d_in[11];
    const float* fc_l0_b   = (const float*)d_in[12];
    const float* equ_fc_2_w= (const float*)d_in[13];
    const float* inv_fc_1_w= (const float*)d_in[14];
    const float* inv_fc_1_b= (const float*)d_in[15];
    const float* ffn_ln_w  = (const float*)d_in[16];
    const float* ffn_ln_b  = (const float*)d_in[17];
    const float* ffn_w1    = (const float*)d_in[18];
    const float* ffn_b1    = (const float*)d_in[19];
    const float* ffn_w2    = (const float*)d_in[20];
    const float* ffn_b2    = (const float*)d_in[21];
    const float* eqn2_w    = (const float*)d_in[22];
    const float* eqn2_b    = (const float*)d_in[23];
    const float* fe1_w     = (const float*)d_in[24];
    const float* gate_w    = (const float*)d_in[25];
    const float* fe2_w     = (const float*)d_in[26];

    const int N = in_sizes[0] / 128;
    const int E = in_sizes[3] / 2;
    const int nblk = (N + 7) / 8;

    float* ws = (float*)d_ws;
    float* feats_ln = ws;
    float* equ_ln   = feats_ln + (size_t)N * 128;
    float* equ1t    = equ_ln   + (size_t)N * 128;
    float* PsP      = equ1t    + (size_t)N * 128;
    float* PtP      = PsP      + (size_t)N * 128;
    float* points4  = PtP      + (size_t)N * 128;   // N*4
    float* fe1P     = points4  + (size_t)N * 4;     // 1024
    float* fe2P     = fe1P + 1024;
    float* gatePa   = fe2P + 1024;
    float* gatePb   = gatePa + 1024;
    float* We2P     = gatePb + 1024;
    int* deg        = (int*)(We2P + 1024);          // N
    int* row_start  = deg + N;
    int* cursor     = row_start + N;
    int* bucket_start  = cursor + N;                // 64
    int* bucket_cursor = bucket_start + 64;         // 64
    int* perm       = bucket_cursor + 64;           // nblk*8 (pad init in csr_scan)
    int* csr_src    = perm + (size_t)nblk * 8;      // E

    hipMemsetAsync(deg, 0, (size_t)N * sizeof(int), stream);

    const int nb_pre = (N + 3) / 4;
    const int nb_hist = (E + 255) / 256;
    pre_and_hist<<<nb_pre + nb_hist, 256, 0, stream>>>(
        N, E, nb_pre, feats, equ, neighbors, points,
        ln1_w, ln1_b, eqn1_w, eqn1_b,
        inv_fc_w, inv_fc_b, equ_fc_w, inv_fc_1_w,
        feats_ln, equ_ln, equ1t, PsP, PtP, points4, deg);

    csr_scan<<<1, 1024, 0, stream>>>(
        N, nblk, deg, row_start, cursor, bucket_start, bucket_cursor, perm,
        fe1_w, fe2_w, gate_w, equ_fc_2_w,
        fe1P, fe2P, gatePa, gatePb, We2P);

    const int nbE = (E + 255) / 256;
    const int nbN = (N + 255) / 256;
    scatter_all<<<nbE + nbN, 256, 0, stream>>>(
        E, N, nbE, neighbors, cursor, csr_src, deg, bucket_cursor, perm);

    float* out_inv = (float*)d_out;
    float* out_equ = out_inv + (size_t)N * 128;

    edge_agg<<<nblk, 256, 0, stream>>>(
        N, perm, row_start, deg, csr_src,
        points4, equ1t, PsP, PtP, feats_ln, equ_ln,
        fc_l0_w, fc_l0_b, inv_fc_1_w, inv_fc_1_b,
        We2P, fe1P, fe2P, gatePa, gatePb, eqn2_w, eqn2_b,
        ffn_ln_w, ffn_ln_b, ffn_w1, ffn_b1, ffn_w2, ffn_b2,
        out_inv, out_equ);
}

// Round 11
// 446.573 us; speedup vs baseline: 1.5787x; 1.5787x over previous
//
#include <hip/hip_runtime.h>
#include <math.h>

#define EPS 1e-5f
#define SQRT3F 1.7320508075688772f

__device__ __forceinline__ float wsum64(float x) {
#pragma unroll
    for (int o = 32; o > 0; o >>= 1) x += __shfl_xor(x, o, 64);
    return x;
}
__device__ __forceinline__ float hsum32(float x) {
#pragma unroll
    for (int o = 16; o > 0; o >>= 1) x += __shfl_xor(x, o, 64);
    return x;
}
__device__ __forceinline__ float sigm(float x) { return 1.f / (1.f + __expf(-x)); }
__device__ __forceinline__ float siluf(float x) { return x * sigm(x); }

// ---------------------------------------------------------------------------
// Kernel 1 (fused): blocks [0, nb_pre): per-node preprocessing (+points4);
// blocks [nb_pre, ...): CSR degree histogram.
// ---------------------------------------------------------------------------
__global__ __launch_bounds__(256) void pre_and_hist(
    int N, int E, int nb_pre,
    const float* __restrict__ feats, const float* __restrict__ equ,
    const int* __restrict__ nbrs, const float* __restrict__ points,
    const float* __restrict__ ln1_w, const float* __restrict__ ln1_b,
    const float* __restrict__ eqn1_w, const float* __restrict__ eqn1_b,
    const float* __restrict__ inv_fc_w, const float* __restrict__ inv_fc_b,
    const float* __restrict__ equ_fc_w, const float* __restrict__ Winv,
    float* __restrict__ feats_ln, float* __restrict__ equ_ln,
    float* __restrict__ equ1t, float* __restrict__ PsP, float* __restrict__ PtP,
    float* __restrict__ points4, int* __restrict__ deg)
{
    if (blockIdx.x >= nb_pre) {
        int i = (blockIdx.x - nb_pre) * 256 + threadIdx.x;
        if (i < E) atomicAdd(&deg[nbrs[E + i]], 1);
        return;
    }

    __shared__ float fl_s[4][128];
    __shared__ float el_s[4][128];
    __shared__ float f1_s[4][32];
    const int w = threadIdx.x >> 6;
    const int lane = threadIdx.x & 63;
    const int n = blockIdx.x * 4 + w;
    const bool act = n < N;
    const int c = lane & 31;
    const int half = lane >> 5;

    if (act && lane == 0) {
        float4 p;
        p.x = points[n * 3 + 0]; p.y = points[n * 3 + 1];
        p.z = points[n * 3 + 2]; p.w = 0.f;
        *(float4*)&points4[n * 4] = p;
    }

    float x0 = 0.f, x1 = 0.f;
    if (act) { x0 = feats[n * 128 + lane]; x1 = feats[n * 128 + 64 + lane]; }
    float s  = wsum64(x0 + x1);
    float sq = wsum64(x0 * x0 + x1 * x1);
    float mu = s * (1.f / 128.f);
    float var = sq * (1.f / 128.f) - mu * mu;
    float rs = rsqrtf(var + EPS);
    float y0 = (x0 - mu) * rs * ln1_w[lane] + ln1_b[lane];
    float y1 = (x1 - mu) * rs * ln1_w[64 + lane] + ln1_b[64 + lane];
    if (act) { feats_ln[n * 128 + lane] = y0; feats_ln[n * 128 + 64 + lane] = y1; }
    fl_s[w][lane] = y0; fl_s[w][64 + lane] = y1;

    float a = 0.f, b = 0.f;
    if (act) { a = equ[n * 128 + lane]; b = equ[n * 128 + 64 + lane]; }
    float a0 = (half == 0) ? a : 0.f;
    float m0 = wsum64(a0) * (1.f / 32.f);
    float f0 = a0 - m0;
    float n0 = wsum64((half == 0) ? f0 * f0 : 0.f) * (1.f / 32.f);
    float rs0 = rsqrtf(n0 + EPS);
    float sq1 = ((half == 1) ? a * a : 0.f) + b * b;
    float n1 = wsum64(sq1) * (1.f / 96.f);
    float rs1 = rsqrtf(n1 + EPS);
    float w1c = eqn1_w[32 + c];
    float ea = (half == 0) ? (f0 * rs0 * eqn1_w[c] + eqn1_b[c]) : (a * rs1 * w1c);
    float eb = b * rs1 * w1c;
    if (act) { equ_ln[n * 128 + lane] = ea; equ_ln[n * 128 + 64 + lane] = eb; }
    el_s[w][lane] = ea; el_s[w][64 + lane] = eb;

    __syncthreads();

    {
        float acc = 0.f;
#pragma unroll 8
        for (int k = 0; k < 64; k++) {
            int kk = half * 64 + k;
            acc += fl_s[w][kk] * inv_fc_w[kk * 32 + c];
        }
        acc += __shfl_xor(acc, 32);
        if (half == 0) f1_s[w][c] = acc + inv_fc_b[c];
    }
    if (act) {
        float acc = 0.f, acc2 = 0.f;
#pragma unroll 8
        for (int k = 0; k < 32; k++) {
            float wv = equ_fc_w[k * 32 + c];
            acc  += el_s[w][half * 32 + k] * wv;
            acc2 += el_s[w][(half + 2) * 32 + k] * wv;
        }
        equ1t[n * 128 + c * 4 + half]     = acc;
        equ1t[n * 128 + c * 4 + half + 2] = acc2;
    }
    __syncthreads();
    if (!act) return;

    {
        const int jj = c;
        float4 aPs = {0.f, 0.f, 0.f, 0.f};
        float4 aPt = {0.f, 0.f, 0.f, 0.f};
#pragma unroll 4
        for (int k = 0; k < 16; k++) {
            int kk = half * 16 + k;
            float x = f1_s[w][kk];
            float4 w4 = *(const float4*)&Winv[kk * 128 + jj * 4];
            float4 v4 = *(const float4*)&Winv[(32 + kk) * 128 + jj * 4];
            aPs.x += x * w4.x; aPs.y += x * w4.y; aPs.z += x * w4.z; aPs.w += x * w4.w;
            aPt.x += x * v4.x; aPt.y += x * v4.y; aPt.z += x * v4.z; aPt.w += x * v4.w;
        }
        aPs.x += __shfl_xor(aPs.x, 32); aPs.y += __shfl_xor(aPs.y, 32);
        aPs.z += __shfl_xor(aPs.z, 32); aPs.w += __shfl_xor(aPs.w, 32);
        aPt.x += __shfl_xor(aPt.x, 32); aPt.y += __shfl_xor(aPt.y, 32);
        aPt.z += __shfl_xor(aPt.z, 32); aPt.w += __shfl_xor(aPt.w, 32);
        if (half == 0) {
            const float* ps = (const float*)&aPs;
            const float* pt = (const float*)&aPt;
#pragma unroll
            for (int i = 0; i < 4; i++) {
                int m = jj * 4 + i;
                PsP[n * 128 + (m & 31) * 4 + (m >> 5)] = ps[i];
                PtP[n * 128 + (m & 31) * 4 + (m >> 5)] = pt[i];
            }
        }
    }
}

// ---------------------------------------------------------------------------
// CSR scan (single block) + DESCENDING degree-bucket prefix + weight packing
// + perm placement (LDS bucket cursors; order within a bucket is arbitrary,
// which is semantically irrelevant).
// ---------------------------------------------------------------------------
__global__ __launch_bounds__(1024) void csr_scan(
    int N, const int* __restrict__ deg,
    int* __restrict__ row_start, int* __restrict__ cursor,
    int* __restrict__ perm,
    const float* __restrict__ fe1, const float* __restrict__ fe2,
    const float* __restrict__ gate_w, const float* __restrict__ We2,
    float* __restrict__ fe1P, float* __restrict__ fe2P,
    float* __restrict__ gatePa, float* __restrict__ gatePb,
    float* __restrict__ We2P)
{
    __shared__ int part[1024];
    __shared__ int hist[64];
    __shared__ int bcur[64];
    const int t = threadIdx.x;

    if (t < 1024) {
        int g = t >> 7, r = t & 127, cc = r >> 2, i = r & 3;
        fe1P[t]   = fe1[(g * 4 + i) * 32 + cc];
        fe2P[t]   = fe2[(g * 4 + i) * 32 + cc];
        gatePa[t] = gate_w[(g * 4 + i) * 64 + cc];
        gatePb[t] = gate_w[(g * 4 + i) * 64 + 32 + cc];
        We2P[t]   = We2[(g * 4 + i) * 32 + cc];
    }

    if (t < 64) hist[t] = 0;
    __syncthreads();

    const int per = (N + 1023) / 1024;
    const int base = t * per;
    int s = 0;
    for (int i = 0; i < per; i++) {
        int idx = base + i;
        if (idx < N) {
            int d = deg[idx];
            s += d;
            atomicAdd(&hist[d < 63 ? d : 63], 1);
        }
    }
    part[t] = s;
    __syncthreads();
    for (int off = 1; off < 1024; off <<= 1) {
        int v = (t >= off) ? part[t - off] : 0;
        __syncthreads();
        part[t] += v;
        __syncthreads();
    }
    int run = (t > 0) ? part[t - 1] : 0;
    for (int i = 0; i < per; i++) {
        int idx = base + i;
        if (idx < N) { row_start[idx] = run; cursor[idx] = run; run += deg[idx]; }
    }
    if (t == 0) {
        int acc = 0;
        for (int b = 63; b >= 0; b--) {   // DESCENDING degree order (LPT, R7)
            bcur[b] = acc;
            acc += hist[b];
        }
    }
    __syncthreads();
    // perm placement: rank within descending-degree order via LDS cursors
    for (int i = 0; i < per; i++) {
        int idx = base + i;
        if (idx < N) {
            int d = deg[idx]; if (d > 63) d = 63;
            int pos = atomicAdd(&bcur[d], 1);
            perm[pos] = idx;
        }
    }
}

// ---------------------------------------------------------------------------
// CSR edge scatter (dst-sorted src ids).
// ---------------------------------------------------------------------------
__global__ __launch_bounds__(256) void csr_scatter(
    int E, const int* __restrict__ nb,
    int* __restrict__ cursor, int* __restrict__ csr_src)
{
    int i = blockIdx.x * 256 + threadIdx.x;
    if (i < E) {
        int d = nb[E + i];
        int s = nb[i];
        int pos = atomicAdd(&cursor[d], 1);
        csr_src[pos] = s;
    }
}

// ---------------------------------------------------------------------------
// Kernel 2: per-DST aggregation + fused equ-gate chain. 32-lane group per
// dst, 8 dsts/block, degree-sorted (descending) via perm. Natural VGPR need
// ~128 (4 waves/SIMD) — no min-waves bound (R5: spill), no grid-stride
// (R8: VGPR 140), no extra fused phase (R10: VGPR 132). This exact structure
// measured 200 µs @ VGPR 128.
// ---------------------------------------------------------------------------
__global__ __launch_bounds__(256) void edge_agg(
    int N,
    const int* __restrict__ perm,
    const int* __restrict__ row_start, const int* __restrict__ deg_arr,
    const int* __restrict__ csr_src,
    const float* __restrict__ points4, const float* __restrict__ equ1t,
    const float* __restrict__ PsP, const float* __restrict__ PtP,
    const float* __restrict__ feats_ln, const float* __restrict__ equ_ln,
    const float* __restrict__ Wl0g, const float* __restrict__ bl0g,
    const float* __restrict__ Winvg, const float* __restrict__ binvg,
    const float* __restrict__ We2P, const float* __restrict__ fe1P,
    const float* __restrict__ fe2P, const float* __restrict__ gatePa,
    const float* __restrict__ gatePb,
    const float* __restrict__ eqn2_w, const float* __restrict__ eqn2_b,
    float* __restrict__ out_inv, float* __restrict__ out_equ)
{
    __shared__ float WeP[32 * 128];   // [k][c][j] = Winv[64+k][j*32+c]  16 KB
    __shared__ float Wl0P[16 * 128];  // [g][c][i] = Wl0[g*4+i][c]        8 KB
    __shared__ float BinvP[128];      // [c][j] = binv[j*32+c]
    __shared__ float bl0s[32];
    __shared__ float scr[8][128];     // per-group scratch                4 KB

    for (int idx = threadIdx.x; idx < 4096; idx += 256) {
        int k = idx >> 7, r = idx & 127, cc = r >> 2, j = r & 3;
        WeP[idx] = Winvg[(64 + k) * 128 + j * 32 + cc];
    }
    for (int idx = threadIdx.x; idx < 2048; idx += 256) {
        int g = idx >> 7, r = idx & 127, cc = r >> 2, i = r & 3;
        Wl0P[idx] = Wl0g[(g * 4 + i) * 32 + cc];
    }
    if (threadIdx.x < 128) BinvP[threadIdx.x] = binvg[(threadIdx.x & 3) * 32 + (threadIdx.x >> 2)];
    if (threadIdx.x < 32) bl0s[threadIdx.x] = bl0g[threadIdx.x];
    __syncthreads();

    const int grp = threadIdx.x >> 5;
    const int c = threadIdx.x & 31;
    const int halfsel = grp & 1;
    const int gid = blockIdx.x * 8 + grp;
    if (gid >= N) return;
    const int n = perm[gid];

    const int start = row_start[n];
    const int len = deg_arr[n];
    const float bl0c = bl0s[c];
    float4 te4 = *(const float4*)&equ1t[n * 128 + c * 4];
    float4 pt4 = *(const float4*)&PtP[n * 128 + c * 4];
    float4 pd4 = *(const float4*)&points4[n * 4];
    float4 base = *(const float4*)&BinvP[c * 4];
    base.x += pt4.x; base.y += pt4.y; base.z += pt4.z; base.w += pt4.w;

    float4 acc = {0.f, 0.f, 0.f, 0.f};
    float4 aer = {0.f, 0.f, 0.f, 0.f};
    int cnt = 0;
    int i = 0;

    for (; i + 2 <= len; i += 2) {
        const int s0 = csr_src[start + i];
        const int s1 = csr_src[start + i + 1];
        float4 a0 = *(const float4*)&equ1t[s0 * 128 + c * 4];
        float4 a1 = *(const float4*)&equ1t[s1 * 128 + c * 4];
        float4 p0 = *(const float4*)&PsP[s0 * 128 + c * 4];
        float4 p1 = *(const float4*)&PsP[s1 * 128 + c * 4];
        float4 q0 = *(const float4*)&points4[s0 * 4];
        float4 q1 = *(const float4*)&points4[s1 * 4];
        float dx0 = SQRT3F * (q0.x - pd4.x);
        float dy0 = SQRT3F * (q0.y - pd4.y);
        float dz0 = SQRT3F * (q0.z - pd4.z);
        float dx1 = SQRT3F * (q1.x - pd4.x);
        float dy1 = SQRT3F * (q1.y - pd4.y);
        float dz1 = SQRT3F * (q1.z - pd4.z);
        scr[grp][c]      = a0.x * te4.x + a0.y * te4.y + a0.z * te4.z + a0.w * te4.w;
        scr[grp][32 + c] = a0.x + a0.y * dx0 + a0.z * dy0 + a0.w * dz0;
        scr[grp][64 + c] = a1.x * te4.x + a1.y * te4.y + a1.z * te4.z + a1.w * te4.w;
        scr[grp][96 + c] = a1.x + a1.y * dx1 + a1.z * dy1 + a1.w * dz1;

        float e0acc = bl0c, e1acc = bl0c;
#pragma unroll
        for (int g = 0; g < 16; g++) {
            float4 w4 = *(const float4*)&Wl0P[g * 128 + c * 4];
            float4 d0 = *(const float4*)&scr[grp][g * 4];
            float4 d1 = *(const float4*)&scr[grp][64 + g * 4];
            e0acc += d0.x * w4.x + d0.y * w4.y + d0.z * w4.z + d0.w * w4.w;
            e1acc += d1.x * w4.x + d1.y * w4.y + d1.z * w4.z + d1.w * w4.w;
        }
        float el0_0 = siluf(e0acc);
        float el0_1 = siluf(e1acc);
        aer.x += el0_0 + el0_1;
        aer.y += a0.y + a1.y; aer.z += a0.z + a1.z; aer.w += a0.w + a1.w;
        scr[grp][c] = el0_0;
        scr[grp][32 + c] = el0_1;

        float4 m0 = base, m1 = base;
        m0.x += p0.x; m0.y += p0.y; m0.z += p0.z; m0.w += p0.w;
        m1.x += p1.x; m1.y += p1.y; m1.z += p1.z; m1.w += p1.w;
#pragma unroll
        for (int g = 0; g < 8; g++) {
            float4 x0 = *(const float4*)&scr[grp][g * 4];
            float4 x1 = *(const float4*)&scr[grp][32 + g * 4];
            const float* xp0 = (const float*)&x0;
            const float* xp1 = (const float*)&x1;
#pragma unroll
            for (int t = 0; t < 4; t++) {
                float4 w4 = *(const float4*)&WeP[(g * 4 + t) * 128 + c * 4];
                float v0 = xp0[t], v1 = xp1[t];
                m0.x += v0 * w4.x; m0.y += v0 * w4.y; m0.z += v0 * w4.z; m0.w += v0 * w4.w;
                m1.x += v1 * w4.x; m1.y += v1 * w4.y; m1.z += v1 * w4.z; m1.w += v1 * w4.w;
            }
        }
        m0.x = siluf(m0.x); m0.y = siluf(m0.y); m0.z = siluf(m0.z); m0.w = siluf(m0.w);
        m1.x = siluf(m1.x); m1.y = siluf(m1.y); m1.z = siluf(m1.z); m1.w = siluf(m1.w);
        acc.x += m0.x + m1.x; acc.y += m0.y + m1.y;
        acc.z += m0.z + m1.z; acc.w += m0.w + m1.w;
        float mx0 = fmaxf(fmaxf(m0.x, m0.y), fmaxf(m0.z, m0.w));
        float mx1 = fmaxf(fmaxf(m1.x, m1.y), fmaxf(m1.z, m1.w));
        unsigned long long b0 = __ballot(mx0 > 0.f);
        unsigned long long b1 = __ballot(mx1 > 0.f);
        cnt += ((unsigned int)(b0 >> (halfsel * 32)) != 0u);
        cnt += ((unsigned int)(b1 >> (halfsel * 32)) != 0u);
    }
    for (; i < len; i++) {
        const int s0 = csr_src[start + i];
        float4 a0 = *(const float4*)&equ1t[s0 * 128 + c * 4];
        float4 p0 = *(const float4*)&PsP[s0 * 128 + c * 4];
        float4 q0 = *(const float4*)&points4[s0 * 4];
        float dx0 = SQRT3F * (q0.x - pd4.x);
        float dy0 = SQRT3F * (q0.y - pd4.y);
        float dz0 = SQRT3F * (q0.z - pd4.z);
        scr[grp][c]      = a0.x * te4.x + a0.y * te4.y + a0.z * te4.z + a0.w * te4.w;
        scr[grp][32 + c] = a0.x + a0.y * dx0 + a0.z * dy0 + a0.w * dz0;
        float e0acc = bl0c;
#pragma unroll
        for (int g = 0; g < 16; g++) {
            float4 w4 = *(const float4*)&Wl0P[g * 128 + c * 4];
            float4 d0 = *(const float4*)&scr[grp][g * 4];
            e0acc += d0.x * w4.x + d0.y * w4.y + d0.z * w4.z + d0.w * w4.w;
        }
        float el0_0 = siluf(e0acc);
        aer.x += el0_0; aer.y += a0.y; aer.z += a0.z; aer.w += a0.w;
        scr[grp][c] = el0_0;
        float4 m0 = base;
        m0.x += p0.x; m0.y += p0.y; m0.z += p0.z; m0.w += p0.w;
#pragma unroll
        for (int g = 0; g < 8; g++) {
            float4 x0 = *(const float4*)&scr[grp][g * 4];
            const float* xp0 = (const float*)&x0;
#pragma unroll
            for (int t = 0; t < 4; t++) {
                float4 w4 = *(const float4*)&WeP[(g * 4 + t) * 128 + c * 4];
                float v0 = xp0[t];
                m0.x += v0 * w4.x; m0.y += v0 * w4.y; m0.z += v0 * w4.z; m0.w += v0 * w4.w;
            }
        }
        m0.x = siluf(m0.x); m0.y = siluf(m0.y); m0.z = siluf(m0.z); m0.w = siluf(m0.w);
        acc.x += m0.x; acc.y += m0.y; acc.z += m0.z; acc.w += m0.w;
        float mx0 = fmaxf(fmaxf(m0.x, m0.y), fmaxf(m0.z, m0.w));
        unsigned long long b0 = __ballot(mx0 > 0.f);
        cnt += ((unsigned int)(b0 >> (halfsel * 32)) != 0u);
    }

    // ---- epilogue: inv_pre write + full equ chain ----
    const float inv_nbn = 1.f / (1.f + (float)cnt);
    out_inv[n * 128 + c]      = (acc.x + feats_ln[n * 128 + c])      * inv_nbn;
    out_inv[n * 128 + 32 + c] = (acc.y + feats_ln[n * 128 + 32 + c]) * inv_nbn;
    out_inv[n * 128 + 64 + c] = (acc.z + feats_ln[n * 128 + 64 + c]) * inv_nbn;
    out_inv[n * 128 + 96 + c] = (acc.w + feats_ln[n * 128 + 96 + c]) * inv_nbn;

    *(float4*)&scr[grp][c * 4] = aer;
    float4 eo = {0.f, 0.f, 0.f, 0.f};
#pragma unroll
    for (int g = 0; g < 8; g++) {
        float4 w4 = *(const float4*)&We2P[g * 128 + c * 4];
        const float* wp = (const float*)&w4;
#pragma unroll
        for (int t = 0; t < 4; t++) {
            float4 a4 = *(const float4*)&scr[grp][(g * 4 + t) * 4];
            float wv = wp[t];
            eo.x += a4.x * wv; eo.y += a4.y * wv; eo.z += a4.z * wv; eo.w += a4.w * wv;
        }
    }
    float4 en;
    en.x = (eo.x + equ_ln[n * 128 + c])      * inv_nbn;
    en.y = (eo.y + equ_ln[n * 128 + 32 + c]) * inv_nbn;
    en.z = (eo.z + equ_ln[n * 128 + 64 + c]) * inv_nbn;
    en.w = (eo.w + equ_ln[n * 128 + 96 + c]) * inv_nbn;

    float m0e = hsum32(en.x) * (1.f / 32.f);
    float f0 = en.x - m0e;
    float n0 = hsum32(f0 * f0) * (1.f / 32.f);
    float rs0 = rsqrtf(n0 + EPS);
    float n1 = hsum32(en.y * en.y + en.z * en.z + en.w * en.w) * (1.f / 96.f);
    float rs1 = rsqrtf(n1 + EPS);
    float w1c = eqn2_w[32 + c];
    float4 ev;
    ev.x = f0 * rs0 * eqn2_w[c] + eqn2_b[c];
    ev.y = en.y * rs1 * w1c;
    ev.z = en.z * rs1 * w1c;
    ev.w = en.w * rs1 * w1c;
    *(float4*)&scr[grp][c * 4] = ev;

    float4 g4 = {0.f, 0.f, 0.f, 0.f};
#pragma unroll
    for (int g = 0; g < 8; g++) {
        float4 w4 = *(const float4*)&fe1P[g * 128 + c * 4];
        const float* wp = (const float*)&w4;
#pragma unroll
        for (int t = 0; t < 4; t++) {
            float4 a4 = *(const float4*)&scr[grp][(g * 4 + t) * 4];
            float wv = wp[t];
            g4.x += a4.x * wv; g4.y += a4.y * wv; g4.z += a4.z * wv; g4.w += a4.w * wv;
        }
    }
    scr[grp][c] = g4.x;

    float aftA = 0.f, aftB = 0.f;
#pragma unroll
    for (int g = 0; g < 8; g++) {
        float4 x4 = *(const float4*)&scr[grp][g * 4];
        float4 wa4 = *(const float4*)&gatePa[g * 128 + c * 4];
        float4 wb4 = *(const float4*)&gatePb[g * 128 + c * 4];
        aftA += x4.x * wa4.x + x4.y * wa4.y + x4.z * wa4.z + x4.w * wa4.w;
        aftB += x4.x * wb4.x + x4.y * wb4.y + x4.z * wb4.z + x4.w * wb4.w;
    }
    float mult = sigm(aftB);
    float4 G;
    G.x = siluf(aftA);
    G.y = g4.y * mult; G.z = g4.z * mult; G.w = g4.w * mult;
    *(float4*)&scr[grp][c * 4] = G;

    float4 oo = {0.f, 0.f, 0.f, 0.f};
#pragma unroll
    for (int g = 0; g < 8; g++) {
        float4 w4 = *(const float4*)&fe2P[g * 128 + c * 4];
        const float* wp = (const float*)&w4;
#pragma unroll
        for (int t = 0; t < 4; t++) {
            float4 a4 = *(const float4*)&scr[grp][(g * 4 + t) * 4];
            float wv = wp[t];
            oo.x += a4.x * wv; oo.y += a4.y * wv; oo.z += a4.z * wv; oo.w += a4.w * wv;
        }
    }
    out_equ[n * 128 + c]      = oo.x + en.x;
    out_equ[n * 128 + 32 + c] = oo.y + en.y;
    out_equ[n * 128 + 64 + c] = oo.z + en.z;
    out_equ[n * 128 + 96 + c] = oo.w + en.w;
}

// ---------------------------------------------------------------------------
// Kernel 3: node_post — inv LN + FFN only. 32 nodes/block.
// ---------------------------------------------------------------------------
__global__ __launch_bounds__(256) void node_post(
    int N,
    const float* __restrict__ ffn_ln_w, const float* __restrict__ ffn_ln_b,
    const float* __restrict__ W1g, const float* __restrict__ b1g,
    const float* __restrict__ W2g, const float* __restrict__ b2g,
    float* __restrict__ io_inv)
{
    __shared__ float ht[128 * 36];
    const int grp = threadIdx.x >> 5;
    const int c = threadIdx.x & 31;

    for (int q = 0; q < 4; q++) {
        const int nd = grp * 4 + q;
        const int n = blockIdx.x * 32 + nd;
        if (n >= N) break;
        float ip0 = io_inv[n * 128 + c];
        float ip1 = io_inv[n * 128 + 32 + c];
        float ip2 = io_inv[n * 128 + 64 + c];
        float ip3 = io_inv[n * 128 + 96 + c];
        float sm = hsum32(ip0 + ip1 + ip2 + ip3) * (1.f / 128.f);
        float sv = hsum32(ip0 * ip0 + ip1 * ip1 + ip2 * ip2 + ip3 * ip3) * (1.f / 128.f) - sm * sm;
        float rsv = rsqrtf(sv + EPS);
        ht[c * 36 + nd]         = (ip0 - sm) * rsv * ffn_ln_w[c]      + ffn_ln_b[c];
        ht[(32 + c) * 36 + nd]  = (ip1 - sm) * rsv * ffn_ln_w[32 + c] + ffn_ln_b[32 + c];
        ht[(64 + c) * 36 + nd]  = (ip2 - sm) * rsv * ffn_ln_w[64 + c] + ffn_ln_b[64 + c];
        ht[(96 + c) * 36 + nd]  = (ip3 - sm) * rsv * ffn_ln_w[96 + c] + ffn_ln_b[96 + c];
    }

    const int wid = threadIdx.x >> 6;
    const int half = (threadIdx.x >> 5) & 1;
    const int ndbase = wid * 8;
    const int nbase = blockIdx.x * 32 + ndbase;

    float4 acc8[8];
#pragma unroll
    for (int j = 0; j < 8; j++) acc8[j] = make_float4(0.f, 0.f, 0.f, 0.f);
    for (int k = 0; k < 64; k++) {
        const int kk = half * 64 + k;
        float4 w4 = *(const float4*)&W1g[kk * 128 + c * 4];
        float4 xA = *(const float4*)&ht[kk * 36 + ndbase];
        float4 xB = *(const float4*)&ht[kk * 36 + ndbase + 4];
        const float* xa = (const float*)&xA;
        const float* xb = (const float*)&xB;
#pragma unroll
        for (int j = 0; j < 4; j++) {
            float v = xa[j];
            acc8[j].x += v * w4.x; acc8[j].y += v * w4.y; acc8[j].z += v * w4.z; acc8[j].w += v * w4.w;
            float u = xb[j];
            acc8[4 + j].x += u * w4.x; acc8[4 + j].y += u * w4.y; acc8[4 + j].z += u * w4.z; acc8[4 + j].w += u * w4.w;
        }
    }
#pragma unroll
    for (int j = 0; j < 8; j++) {
        acc8[j].x += __shfl_xor(acc8[j].x, 32); acc8[j].y += __shfl_xor(acc8[j].y, 32);
        acc8[j].z += __shfl_xor(acc8[j].z, 32); acc8[j].w += __shfl_xor(acc8[j].w, 32);
    }
    if (half == 0) {
        float4 b4 = *(const float4*)&b1g[c * 4];
#pragma unroll
        for (int j = 0; j < 8; j++) {
            ht[(4 * c + 0) * 36 + ndbase + j] = fmaxf(acc8[j].x + b4.x, 0.f);
            ht[(4 * c + 1) * 36 + ndbase + j] = fmaxf(acc8[j].y + b4.y, 0.f);
            ht[(4 * c + 2) * 36 + ndbase + j] = fmaxf(acc8[j].z + b4.z, 0.f);
            ht[(4 * c + 3) * 36 + ndbase + j] = fmaxf(acc8[j].w + b4.w, 0.f);
        }
    }
#pragma unroll
    for (int j = 0; j < 8; j++) acc8[j] = make_float4(0.f, 0.f, 0.f, 0.f);
    for (int k = 0; k < 64; k++) {
        const int kk = half * 64 + k;
        float4 w4 = *(const float4*)&W2g[kk * 128 + c * 4];
        float4 xA = *(const float4*)&ht[kk * 36 + ndbase];
        float4 xB = *(const float4*)&ht[kk * 36 + ndbase + 4];
        const float* xa = (const float*)&xA;
        const float* xb = (const float*)&xB;
#pragma unroll
        for (int j = 0; j < 4; j++) {
            float v = xa[j];
            acc8[j].x += v * w4.x; acc8[j].y += v * w4.y; acc8[j].z += v * w4.z; acc8[j].w += v * w4.w;
            float u = xb[j];
            acc8[4 + j].x += u * w4.x; acc8[4 + j].y += u * w4.y; acc8[4 + j].z += u * w4.z; acc8[4 + j].w += u * w4.w;
        }
    }
#pragma unroll
    for (int j = 0; j < 8; j++) {
        acc8[j].x += __shfl_xor(acc8[j].x, 32); acc8[j].y += __shfl_xor(acc8[j].y, 32);
        acc8[j].z += __shfl_xor(acc8[j].z, 32); acc8[j].w += __shfl_xor(acc8[j].w, 32);
    }
    if (half == 0) {
        float4 b4 = *(const float4*)&b2g[c * 4];
#pragma unroll
        for (int j = 0; j < 8; j++) {
            const int n = nbase + j;
            if (n < N) {
                float4 ipre = *(const float4*)&io_inv[n * 128 + c * 4];
                float4 o;
                o.x = acc8[j].x + b4.x + ipre.x;
                o.y = acc8[j].y + b4.y + ipre.y;
                o.z = acc8[j].z + b4.z + ipre.z;
                o.w = acc8[j].w + b4.w + ipre.w;
                *(float4*)&io_inv[n * 128 + c * 4] = o;
            }
        }
    }
}

// ---------------------------------------------------------------------------
extern "C" void kernel_launch(void* const* d_in, const int* in_sizes, int n_in,
                              void* d_out, int out_size, void* d_ws, size_t ws_size,
                              hipStream_t stream)
{
    const float* feats     = (const float*)d_in[0];
    const float* equ       = (const float*)d_in[1];
    const float* points    = (const float*)d_in[2];
    const int*   neighbors = (const int*)d_in[3];
    const float* ln1_w     = (const float*)d_in[4];
    const float* ln1_b     = (const float*)d_in[5];
    const float* eqn1_w    = (const float*)d_in[6];
    const float* eqn1_b    = (const float*)d_in[7];
    const float* inv_fc_w  = (const float*)d_in[8];
    const float* inv_fc_b  = (const float*)d_in[9];
    const float* equ_fc_w  = (const float*)d_in[10];
    const float* fc_l0_w   = (const float*)d_in[11];
    const float* fc_l0_b   = (const float*)d_in[12];
    const float* equ_fc_2_w= (const float*)d_in[13];
    const float* inv_fc_1_w= (const float*)d_in[14];
    const float* inv_fc_1_b= (const float*)d_in[15];
    const float* ffn_ln_w  = (const float*)d_in[16];
    const float* ffn_ln_b  = (const float*)d_in[17];
    const float* ffn_w1    = (const float*)d_in[18];
    const float* ffn_b1    = (const float*)d_in[19];
    const float* ffn_w2    = (const float*)d_in[20];
    const float* ffn_b2    = (const float*)d_in[21];
    const float* eqn2_w    = (const float*)d_in[22];
    const float* eqn2_b    = (const float*)d_in[23];
    const float* fe1_w     = (const float*)d_in[24];
    const float* gate_w    = (const float*)d_in[25];
    const float* fe2_w     = (const float*)d_in[26];

    const int N = in_sizes[0] / 128;
    const int E = in_sizes[3] / 2;

    float* ws = (float*)d_ws;
    float* feats_ln = ws;
    float* equ_ln   = feats_ln + (size_t)N * 128;
    float* equ1t    = equ_ln   + (size_t)N * 128;
    float* PsP      = equ1t    + (size_t)N * 128;
    float* PtP      = PsP      + (size_t)N * 128;
    float* points4  = PtP      + (size_t)N * 128;   // N*4
    float* fe1P     = points4  + (size_t)N * 4;     // 1024
    float* fe2P     = fe1P + 1024;
    float* gatePa   = fe2P + 1024;
    float* gatePb   = gatePa + 1024;
    float* We2P     = gatePb + 1024;
    int* deg        = (int*)(We2P + 1024);          // N
    int* row_start  = deg + N;
    int* cursor     = row_start + N;
    int* perm       = cursor + N;                   // N
    int* csr_src    = perm + N;                     // E

    hipMemsetAsync(deg, 0, (size_t)N * sizeof(int), stream);

    const int nb_pre = (N + 3) / 4;
    const int nb_hist = (E + 255) / 256;
    pre_and_hist<<<nb_pre + nb_hist, 256, 0, stream>>>(
        N, E, nb_pre, feats, equ, neighbors, points,
        ln1_w, ln1_b, eqn1_w, eqn1_b,
        inv_fc_w, inv_fc_b, equ_fc_w, inv_fc_1_w,
        feats_ln, equ_ln, equ1t, PsP, PtP, points4, deg);

    csr_scan<<<1, 1024, 0, stream>>>(
        N, deg, row_start, cursor, perm,
        fe1_w, fe2_w, gate_w, equ_fc_2_w,
        fe1P, fe2P, gatePa, gatePb, We2P);

    csr_scatter<<<(E + 255) / 256, 256, 0, stream>>>(
        E, neighbors, cursor, csr_src);

    float* out_inv = (float*)d_out;
    float* out_equ = out_inv + (size_t)N * 128;

    edge_agg<<<(N + 7) / 8, 256, 0, stream>>>(
        N, perm, row_start, deg, csr_src,
        points4, equ1t, PsP, PtP, feats_ln, equ_ln,
        fc_l0_w, fc_l0_b, inv_fc_1_w, inv_fc_1_b,
        We2P, fe1P, fe2P, gatePa, gatePb, eqn2_w, eqn2_b,
        out_inv, out_equ);

    node_post<<<(N + 31) / 32, 256, 0, stream>>>(
        N, ffn_ln_w, ffn_ln_b, ffn_w1, ffn_b1, ffn_w2, ffn_b2,
        out_inv);
}